// Round 1
// baseline (141.140 us; speedup 1.0000x reference)
//
#include <hip/hip_runtime.h>
#include <math.h>

#define EMB 512
#define NM 5
#define HID 64
#define NQ 2048
#define NP 256

typedef __attribute__((ext_vector_type(8))) short short8;   // 8 bf16 = 16B
typedef __attribute__((ext_vector_type(4))) float floatx4;
typedef __attribute__((ext_vector_type(4))) float vf4;      // pk-math vectors
typedef __attribute__((ext_vector_type(2))) float vf2;

// ws layout (bytes)
#define A_BY 0u                    // A[m][q][h] f32 (+b1)   2,621,440
#define B_BY 2621440u              // B[m][h/4][p][h%4] f32    327,680

#define LST 72                     // LDS row stride in shorts (144B, 16B-aligned)

__device__ inline unsigned short bfr(float f) {            // f32 -> bf16 RNE
    unsigned u = __float_as_uint(f);
    u += 0x7FFFu + ((u >> 16) & 1u);
    return (unsigned short)(u >> 16);
}

__device__ inline void cvt8(float4 a, float4 b, short8& hi, short8& lo) {
#define C1(I, V) { unsigned short h_ = bfr(V); hi[I] = (short)h_; \
    lo[I] = (short)bfr(V - __uint_as_float(((unsigned)h_) << 16)); }
    C1(0, a.x) C1(1, a.y) C1(2, a.z) C1(3, a.w)
    C1(4, b.x) C1(5, b.y) C1(6, b.z) C1(7, b.w)
#undef C1
}
__device__ inline void cvt8hi(float4 a, float4 b, short8& hi) {
    hi[0] = (short)bfr(a.x); hi[1] = (short)bfr(a.y);
    hi[2] = (short)bfr(a.z); hi[3] = (short)bfr(a.w);
    hi[4] = (short)bfr(b.x); hi[5] = (short)bfr(b.y);
    hi[6] = (short)bfr(b.z); hi[7] = (short)bfr(b.w);
}

// ---------------------------------------------------------------------------
// Kernel 1: LDS double-buffered MFMA GEMM — ONE barrier per 64-K chunk.
// (unchanged from the verified 92.6 µs version; absmax 9.8e-4 comes from the
// 2-term Ootomo X-staging here, do not perturb)
__global__ __launch_bounds__(256) void gemm_v3(const float* __restrict__ Q,
                                               const float* __restrict__ P,
                                               const float* __restrict__ W1,
                                               const float* __restrict__ b1,
                                               float* __restrict__ A,
                                               float* __restrict__ Bv) {
    __shared__ short XH[2][16 * LST];
    __shared__ short WH[2][64 * LST];
    __shared__ short WL[2][64 * LST];

    int tid  = threadIdx.x;
    int lane = tid & 63;
    int ht   = tid >> 6;
    int m    = blockIdx.x % 5;
    int rt   = blockIdx.x / 5;           // 0..143
    int r0   = rt * 16;
    bool isQ = rt < 128;

    int wrow = tid >> 3;                 // 0..31  (also rows +32)
    int wg8  = (tid & 7) * 8;            // k offset within 64-chunk
    const float* wb  = W1 + (size_t)m * 64 * 1024 + (isQ ? 0 : EMB);
    const float* wp0 = wb + (size_t)wrow * 1024 + wg8;
    const float* wp1 = wb + (size_t)(wrow + 32) * 1024 + wg8;
    bool hasX = tid < 128;
    int xrow  = tid >> 3;                // 0..15 when hasX
    const float* xp = (isQ ? Q + (size_t)(r0 + xrow) * EMB
                           : P + (size_t)(r0 - NQ + xrow) * EMB) + wg8;

    int arix = (lane & 15) * LST + (lane >> 4) * 8;
    int brix = (ht * 16 + (lane & 15)) * LST + (lane >> 4) * 8;

    floatx4 ac = {0, 0, 0, 0};
    float4 w00, w01, w10, w11, x0, x1;

    w00 = *(const float4*)&wp0[0]; w01 = *(const float4*)&wp0[4];
    w10 = *(const float4*)&wp1[0]; w11 = *(const float4*)&wp1[4];
    if (hasX) { x0 = *(const float4*)&xp[0]; x1 = *(const float4*)&xp[4]; }
    {
        short8 hi, lo;
        cvt8(w00, w01, hi, lo);
        *(short8*)&WH[0][wrow * LST + wg8] = hi;
        *(short8*)&WL[0][wrow * LST + wg8] = lo;
        cvt8(w10, w11, hi, lo);
        *(short8*)&WH[0][(wrow + 32) * LST + wg8] = hi;
        *(short8*)&WL[0][(wrow + 32) * LST + wg8] = lo;
        if (hasX) { short8 xh; cvt8hi(x0, x1, xh);
                    *(short8*)&XH[0][xrow * LST + wg8] = xh; }
    }

#pragma unroll 1
    for (int c = 0; c < 8; ++c) {
        int cur = c & 1;
        if (c < 7) {
            int k0 = (c + 1) * 64;
            w00 = *(const float4*)&wp0[k0]; w01 = *(const float4*)&wp0[k0 + 4];
            w10 = *(const float4*)&wp1[k0]; w11 = *(const float4*)&wp1[k0 + 4];
            if (hasX) { x0 = *(const float4*)&xp[k0]; x1 = *(const float4*)&xp[k0 + 4]; }
        }
        __syncthreads();

#pragma unroll
        for (int s = 0; s < 2; ++s) {
            short8 Ah = *(const short8*)&XH[cur][arix + s * 32];
            short8 Bh = *(const short8*)&WH[cur][brix + s * 32];
            short8 Bl = *(const short8*)&WL[cur][brix + s * 32];
            ac = __builtin_amdgcn_mfma_f32_16x16x32_bf16(Ah, Bl, ac, 0, 0, 0);
            ac = __builtin_amdgcn_mfma_f32_16x16x32_bf16(Ah, Bh, ac, 0, 0, 0);
        }

        if (c < 7) {
            int nb = cur ^ 1;
            short8 hi, lo;
            cvt8(w00, w01, hi, lo);
            *(short8*)&WH[nb][wrow * LST + wg8] = hi;
            *(short8*)&WL[nb][wrow * LST + wg8] = lo;
            cvt8(w10, w11, hi, lo);
            *(short8*)&WH[nb][(wrow + 32) * LST + wg8] = hi;
            *(short8*)&WL[nb][(wrow + 32) * LST + wg8] = lo;
            if (hasX) { short8 xh; cvt8hi(x0, x1, xh);
                        *(short8*)&XH[nb][xrow * LST + wg8] = xh; }
        }
    }

    int col  = lane & 15;
    int rloc = (lane >> 4) * 4;
    int hh   = ht * 16 + col;
    int rr   = r0 + rloc;

    if (isQ) {
        float bb = b1[m * 64 + hh];
        float* dst = &A[((size_t)m * NQ + rr) * HID + hh];
        dst[0 * HID] = ac.x + bb; dst[1 * HID] = ac.y + bb;
        dst[2 * HID] = ac.z + bb; dst[3 * HID] = ac.w + bb;
    } else {
        int p = rr - NQ;
        float* dst = &Bv[(((size_t)(m * 16 + (hh >> 2))) * NP + p) * 4 + (hh & 3)];
        dst[0 * 4] = ac.x; dst[1 * 4] = ac.y; dst[2 * 4] = ac.z; dst[3 * 4] = ac.w;
    }
}

// ---------------------------------------------------------------------------
// Kernel 2: fused relu-ensemble + mean/std/exp.
// R14: was L2-BW-bound (each 2-q block re-read all 327 KB of Bv -> 335 MB of
// L2 traffic ~ 9.7 us) with a 6.4 us scalar-VALU floor underneath.
//  - 8 q/thread (grid 256 = 1 block/CU): Bv L2 traffic /4 -> 84 MB ~ 2.4 us.
//    B[m] held in 16 float4 regs, next-m prefetched into a second reg set.
//  - packed fp32 (v_pk_add/max/fma on adjacent-h float2 pairs; A/B/W2 are all
//    h-contiguous so pairs are natural 8B loads, no broadcasts): inner loop
//    3 pk-ops per 2 h instead of 6 scalar ops -> VALU floor 6.4 -> 3.2 us.
// A/W2/b2 pointers are block-uniform -> scalar loads, no extra VMEM.
__global__ __launch_bounds__(256) void fused_main(const float* __restrict__ A,
                                                  const float* __restrict__ Bv,
                                                  const float* __restrict__ W2,
                                                  const float* __restrict__ b2,
                                                  float* __restrict__ out) {
    int p  = threadIdx.x;            // 0..255
    int q0 = blockIdx.x * 8;

    const vf4* Bq = (const vf4*)Bv + p;

    float s1[8], s2[8];
#pragma unroll
    for (int i = 0; i < 8; ++i) { s1[i] = 0.f; s2[i] = 0.f; }

    vf4 Bc[16], Bn[16];
#pragma unroll
    for (int j = 0; j < 16; ++j) Bc[j] = Bq[j * NP];      // m=0

#pragma unroll 1
    for (int m = 0; m < NM; ++m) {
        if (m < NM - 1) {                                  // prefetch next m
            const vf4* bn = Bq + (size_t)(m + 1) * 16 * NP;
#pragma unroll
            for (int j = 0; j < 16; ++j) Bn[j] = bn[j * NP];
        }

        const float* Am = A + ((size_t)m * NQ + q0) * HID; // block-uniform
        const float* Wm = W2 + m * HID;                    // block-uniform
        float bb = b2[m];

#pragma unroll
        for (int qi = 0; qi < 8; ++qi) {
            const float* Ar = Am + qi * HID;
            vf2 acc = {0.f, 0.f};
#pragma unroll
            for (int j = 0; j < 16; ++j) {
                vf2 a0 = *(const vf2*)&Ar[j * 4 + 0];
                vf2 a1 = *(const vf2*)&Ar[j * 4 + 2];
                vf2 w0 = *(const vf2*)&Wm[j * 4 + 0];
                vf2 w1 = *(const vf2*)&Wm[j * 4 + 2];
                vf2 z  = {0.f, 0.f};
                vf2 t0 = __builtin_elementwise_max(a0 + Bc[j].xy, z);
                vf2 t1 = __builtin_elementwise_max(a1 + Bc[j].zw, z);
                acc = t0 * w0 + acc;                       // contracts to v_pk_fma_f32
                acc = t1 * w1 + acc;
            }
            float x = acc.x + acc.y + bb;
            s1[qi] += x;
            s2[qi] = fmaf(x, x, s2[qi]);
        }

        if (m < NM - 1) {
#pragma unroll
            for (int j = 0; j < 16; ++j) Bc[j] = Bn[j];
        }
    }

#pragma unroll
    for (int qi = 0; qi < 8; ++qi) {
        float mean = s1[qi] * 0.2f;
        float var  = fmaxf((s2[qi] - s1[qi] * s1[qi] * 0.2f) * 0.25f, 0.f);
        out[(size_t)(q0 + qi) * NP + p] = mean * __expf(-sqrtf(var));
    }
}

// ---------------------------------------------------------------------------
extern "C" void kernel_launch(void* const* d_in, const int* in_sizes, int n_in,
                              void* d_out, int out_size, void* d_ws, size_t ws_size,
                              hipStream_t stream) {
    const float* Q  = (const float*)d_in[0];   // (2048, 512)
    const float* P  = (const float*)d_in[1];   // (256, 512)
    const float* W1 = (const float*)d_in[2];   // (5, 64, 1024)
    const float* b1 = (const float*)d_in[3];   // (5, 64)
    const float* W2 = (const float*)d_in[4];   // (5, 64)
    const float* b2 = (const float*)d_in[5];   // (5,)
    float* out = (float*)d_out;

    char*  ws = (char*)d_ws;
    float* A  = (float*)(ws + A_BY);
    float* B  = (float*)(ws + B_BY);

    gemm_v3<<<720, 256, 0, stream>>>(Q, P, W1, b1, A, B);
    fused_main<<<256, 256, 0, stream>>>(A, B, W2, b2, out);
}

// Round 2
// 93.567 us; speedup vs baseline: 1.5084x; 1.5084x over previous
//
#include <hip/hip_runtime.h>
#include <math.h>

#define EMB 512
#define NM 5
#define HID 64
#define NQ 2048
#define NP 256

typedef __attribute__((ext_vector_type(8))) short short8;   // 8 bf16 = 16B
typedef __attribute__((ext_vector_type(4))) float floatx4;
typedef __attribute__((ext_vector_type(4))) float vf4;      // pk-math vectors
typedef __attribute__((ext_vector_type(2))) float vf2;

// ws layout (bytes)
#define A_BY 0u                    // A[m][q][h] f32 (+b1)   2,621,440
#define B_BY 2621440u              // B[m][h/4][p][h%4] f32    327,680

#define LST 72                     // LDS row stride in shorts (144B, 16B-aligned)

__device__ inline unsigned short bfr(float f) {            // f32 -> bf16 RNE
    unsigned u = __float_as_uint(f);
    u += 0x7FFFu + ((u >> 16) & 1u);
    return (unsigned short)(u >> 16);
}

__device__ inline void cvt8(float4 a, float4 b, short8& hi, short8& lo) {
#define C1(I, V) { unsigned short h_ = bfr(V); hi[I] = (short)h_; \
    lo[I] = (short)bfr(V - __uint_as_float(((unsigned)h_) << 16)); }
    C1(0, a.x) C1(1, a.y) C1(2, a.z) C1(3, a.w)
    C1(4, b.x) C1(5, b.y) C1(6, b.z) C1(7, b.w)
#undef C1
}
__device__ inline void cvt8hi(float4 a, float4 b, short8& hi) {
    hi[0] = (short)bfr(a.x); hi[1] = (short)bfr(a.y);
    hi[2] = (short)bfr(a.z); hi[3] = (short)bfr(a.w);
    hi[4] = (short)bfr(b.x); hi[5] = (short)bfr(b.y);
    hi[6] = (short)bfr(b.z); hi[7] = (short)bfr(b.w);
}

// ---------------------------------------------------------------------------
// Kernel 1: LDS double-buffered MFMA GEMM — ONE barrier per 64-K chunk.
// (unchanged from the verified 92.6 µs version; absmax 9.8e-4 comes from the
// 2-term Ootomo X-staging here, do not perturb)
__global__ __launch_bounds__(256) void gemm_v3(const float* __restrict__ Q,
                                               const float* __restrict__ P,
                                               const float* __restrict__ W1,
                                               const float* __restrict__ b1,
                                               float* __restrict__ A,
                                               float* __restrict__ Bv) {
    __shared__ short XH[2][16 * LST];
    __shared__ short WH[2][64 * LST];
    __shared__ short WL[2][64 * LST];

    int tid  = threadIdx.x;
    int lane = tid & 63;
    int ht   = tid >> 6;
    int m    = blockIdx.x % 5;
    int rt   = blockIdx.x / 5;           // 0..143
    int r0   = rt * 16;
    bool isQ = rt < 128;

    int wrow = tid >> 3;                 // 0..31  (also rows +32)
    int wg8  = (tid & 7) * 8;            // k offset within 64-chunk
    const float* wb  = W1 + (size_t)m * 64 * 1024 + (isQ ? 0 : EMB);
    const float* wp0 = wb + (size_t)wrow * 1024 + wg8;
    const float* wp1 = wb + (size_t)(wrow + 32) * 1024 + wg8;
    bool hasX = tid < 128;
    int xrow  = tid >> 3;                // 0..15 when hasX
    const float* xp = (isQ ? Q + (size_t)(r0 + xrow) * EMB
                           : P + (size_t)(r0 - NQ + xrow) * EMB) + wg8;

    int arix = (lane & 15) * LST + (lane >> 4) * 8;
    int brix = (ht * 16 + (lane & 15)) * LST + (lane >> 4) * 8;

    floatx4 ac = {0, 0, 0, 0};
    float4 w00, w01, w10, w11, x0, x1;

    w00 = *(const float4*)&wp0[0]; w01 = *(const float4*)&wp0[4];
    w10 = *(const float4*)&wp1[0]; w11 = *(const float4*)&wp1[4];
    if (hasX) { x0 = *(const float4*)&xp[0]; x1 = *(const float4*)&xp[4]; }
    {
        short8 hi, lo;
        cvt8(w00, w01, hi, lo);
        *(short8*)&WH[0][wrow * LST + wg8] = hi;
        *(short8*)&WL[0][wrow * LST + wg8] = lo;
        cvt8(w10, w11, hi, lo);
        *(short8*)&WH[0][(wrow + 32) * LST + wg8] = hi;
        *(short8*)&WL[0][(wrow + 32) * LST + wg8] = lo;
        if (hasX) { short8 xh; cvt8hi(x0, x1, xh);
                    *(short8*)&XH[0][xrow * LST + wg8] = xh; }
    }

#pragma unroll 1
    for (int c = 0; c < 8; ++c) {
        int cur = c & 1;
        if (c < 7) {
            int k0 = (c + 1) * 64;
            w00 = *(const float4*)&wp0[k0]; w01 = *(const float4*)&wp0[k0 + 4];
            w10 = *(const float4*)&wp1[k0]; w11 = *(const float4*)&wp1[k0 + 4];
            if (hasX) { x0 = *(const float4*)&xp[k0]; x1 = *(const float4*)&xp[k0 + 4]; }
        }
        __syncthreads();

#pragma unroll
        for (int s = 0; s < 2; ++s) {
            short8 Ah = *(const short8*)&XH[cur][arix + s * 32];
            short8 Bh = *(const short8*)&WH[cur][brix + s * 32];
            short8 Bl = *(const short8*)&WL[cur][brix + s * 32];
            ac = __builtin_amdgcn_mfma_f32_16x16x32_bf16(Ah, Bl, ac, 0, 0, 0);
            ac = __builtin_amdgcn_mfma_f32_16x16x32_bf16(Ah, Bh, ac, 0, 0, 0);
        }

        if (c < 7) {
            int nb = cur ^ 1;
            short8 hi, lo;
            cvt8(w00, w01, hi, lo);
            *(short8*)&WH[nb][wrow * LST + wg8] = hi;
            *(short8*)&WL[nb][wrow * LST + wg8] = lo;
            cvt8(w10, w11, hi, lo);
            *(short8*)&WH[nb][(wrow + 32) * LST + wg8] = hi;
            *(short8*)&WL[nb][(wrow + 32) * LST + wg8] = lo;
            if (hasX) { short8 xh; cvt8hi(x0, x1, xh);
                        *(short8*)&XH[nb][xrow * LST + wg8] = xh; }
        }
    }

    int col  = lane & 15;
    int rloc = (lane >> 4) * 4;
    int hh   = ht * 16 + col;
    int rr   = r0 + rloc;

    if (isQ) {
        float bb = b1[m * 64 + hh];
        float* dst = &A[((size_t)m * NQ + rr) * HID + hh];
        dst[0 * HID] = ac.x + bb; dst[1 * HID] = ac.y + bb;
        dst[2 * HID] = ac.z + bb; dst[3 * HID] = ac.w + bb;
    } else {
        int p = rr - NQ;
        float* dst = &Bv[(((size_t)(m * 16 + (hh >> 2))) * NP + p) * 4 + (hh & 3)];
        dst[0 * 4] = ac.x; dst[1 * 4] = ac.y; dst[2 * 4] = ac.z; dst[3 * 4] = ac.w;
    }
}

// ---------------------------------------------------------------------------
// Kernel 2: fused relu-ensemble + mean/std/exp.
// R15 post-mortem of R14: grid 256 (1 wave/SIMD) + Bc+Bn=128 VGPR forced
// spills (VGPR capped at 116) -> 68.8 us, VALUBusy 25% was spill code.
// R15 design: B L2 traffic scales with (#blocks x p-span). Shrink p-span,
// not the grid:
//   grid 1024 = 4 p-tiles(64) x 256 q-tiles(8); block 256 thr = 64p x 4 qg,
//   2 q per thread -> 4 blocks/CU (16 waves/CU), B traffic 82 MB (~2.4 us L2).
//   qg in LOW tid bits: a wave reads only 16 distinct B float4 (256B
//   contiguous) -> coalescer dedups the q-redundancy; single Bc[16] reg set
//   (64 VGPR), no double-buffer, no spill.
//   A slice (5x8x64 f32 = 10 KB) staged in LDS, row stride 68 floats:
//   qg-step = 136 words = 8 mod 32 banks -> conflict-free ds_read_b64.
//   pk-fp32 math kept (VALU floor ~3.2 us).
#define AST 68                      // LDS A row stride in floats
__global__ __launch_bounds__(256) void fused_main(const float* __restrict__ A,
                                                  const float* __restrict__ Bv,
                                                  const float* __restrict__ W2,
                                                  const float* __restrict__ b2,
                                                  float* __restrict__ out) {
    __shared__ float As[NM][8][AST];          // 10,880 B

    int tid  = threadIdx.x;
    int bp   = (blockIdx.x & 3) * 64;         // p-tile base
    int q0   = (blockIdx.x >> 2) * 8;         // q-tile base
    int p    = tid >> 2;                      // 0..63 within p-tile
    int qg   = tid & 3;                       // 0..3

    // stage A slice: 5 x 8 x 64 floats = 640 float4
    {
        const float4* Ag = (const float4*)A;  // f4 idx (m*NQ+q)*16 + j
        for (int i = tid; i < 640; i += 256) {
            int m = i >> 7, rem = i & 127;
            int qr = rem >> 4, j = rem & 15;
            *(float4*)&As[m][qr][j * 4] =
                Ag[(size_t)m * (NQ * 16) + (size_t)(q0 + qr) * 16 + j];
        }
    }
    __syncthreads();

    const vf4* Bq = (const vf4*)Bv + (bp + p);   // f4 idx (m*16+j)*NP + p

    float s1[2] = {0.f, 0.f}, s2[2] = {0.f, 0.f};

#pragma unroll 1
    for (int m = 0; m < NM; ++m) {
        vf4 Bc[16];
#pragma unroll
        for (int j = 0; j < 16; ++j) Bc[j] = Bq[(m * 16 + j) * NP];

        const float* Wm = W2 + m * HID;           // block-uniform -> scalar
        float bb = b2[m];

#pragma unroll
        for (int qi = 0; qi < 2; ++qi) {
            const float* Ar = &As[m][qg * 2 + qi][0];
            vf2 acc = {0.f, 0.f};
#pragma unroll
            for (int j = 0; j < 16; ++j) {
                vf2 a0 = *(const vf2*)&Ar[j * 4 + 0];
                vf2 a1 = *(const vf2*)&Ar[j * 4 + 2];
                vf2 w0 = *(const vf2*)&Wm[j * 4 + 0];
                vf2 w1 = *(const vf2*)&Wm[j * 4 + 2];
                vf2 z  = {0.f, 0.f};
                vf2 t0 = __builtin_elementwise_max(a0 + Bc[j].xy, z);
                vf2 t1 = __builtin_elementwise_max(a1 + Bc[j].zw, z);
                acc = t0 * w0 + acc;              // v_pk_fma_f32
                acc = t1 * w1 + acc;
            }
            float x = acc.x + acc.y + bb;
            s1[qi] += x;
            s2[qi] = fmaf(x, x, s2[qi]);
        }
    }

#pragma unroll
    for (int qi = 0; qi < 2; ++qi) {
        float mean = s1[qi] * 0.2f;
        float var  = fmaxf((s2[qi] - s1[qi] * s1[qi] * 0.2f) * 0.25f, 0.f);
        out[(size_t)(q0 + qg * 2 + qi) * NP + bp + p] =
            mean * __expf(-sqrtf(var));
    }
}

// ---------------------------------------------------------------------------
extern "C" void kernel_launch(void* const* d_in, const int* in_sizes, int n_in,
                              void* d_out, int out_size, void* d_ws, size_t ws_size,
                              hipStream_t stream) {
    const float* Q  = (const float*)d_in[0];   // (2048, 512)
    const float* P  = (const float*)d_in[1];   // (256, 512)
    const float* W1 = (const float*)d_in[2];   // (5, 64, 1024)
    const float* b1 = (const float*)d_in[3];   // (5, 64)
    const float* W2 = (const float*)d_in[4];   // (5, 64)
    const float* b2 = (const float*)d_in[5];   // (5,)
    float* out = (float*)d_out;

    char*  ws = (char*)d_ws;
    float* A  = (float*)(ws + A_BY);
    float* B  = (float*)(ws + B_BY);

    gemm_v3<<<720, 256, 0, stream>>>(Q, P, W1, b1, A, B);
    fused_main<<<1024, 256, 0, stream>>>(A, B, W2, b2, out);
}